// Round 3
// baseline (198.838 us; speedup 1.0000x reference)
//
#include <hip/hip_runtime.h>

// OpeningLoss2D: grey_opening(x, size=2) per 2D map, then mean((x - open)^2).
// size=2 -> erosion offsets [-1,0], dilation offsets [0,+1]; symmetric pad of
// width 1 == edge clamp. Separable min/max streamed through registers.
//
// Layout: each wave owns a 256-col x 16-row tile (lane = 4 contiguous cols via
// one float4 load -> 100% cache-line utilization per load instruction).
// Column neighbors: two independent shuffles right after the load; seam/edge
// column via a single-lane scalar dword per row. 8192 waves = 32 waves/CU.

constexpr int W = 512;
constexpr int H = 512;
constexpr int RPW = 16;                 // rows per tile
constexpr int STRIPS = H / RPW;         // 32

__global__ __launch_bounds__(256) void open_loss(
    const float* __restrict__ x, float* __restrict__ out, float invN) {
  const int gtid = blockIdx.x * blockDim.x + threadIdx.x;
  const int wave = gtid >> 6;
  const int lane = threadIdx.x & 63;
  const int img = wave >> 6;            // 64 waves per image
  const int rem = wave & 63;
  const int half = rem & 1;             // 0: cols 0..255, 1: cols 256..511
  const int strip = rem >> 1;

  const float* base = x + ((size_t)img * H + (size_t)strip * RPW) * W +
                      (size_t)half * 256 + (size_t)lane * 4;
  const int extLane = half ? 0 : 63;    // lane that needs the cross-seam col
  const int extOff = half ? -1 : 4;     // x[255] for right half, x[256] for left

  float v[4];                           // current row x (4 cols/lane)
  float cm[5];                          // col-min of cols 4l-? : cm[k]=min(x[c-1],x[c]), cm[4] for col 4l+4
  float pcm[5];                         // previous row's col-mins
  float xp[4], dmp[4];                  // x and dilation-row-max of row being finished
  float acc = 0.f;

  auto loadrow = [&](int drow) {
    const float* p = base + (ptrdiff_t)drow * W;
    const float4 a = *reinterpret_cast<const float4*>(p);
    v[0] = a.x; v[1] = a.y; v[2] = a.z; v[3] = a.w;
    float ext = 0.f;
    if (lane == extLane) ext = p[extOff];   // 1 active lane, 1 line touch
    float vleft = __shfl_up(v[3], 1);       // lane-1's last col
    float vn0 = __shfl_down(v[0], 1);       // lane+1's first col
    if (lane == 0) vleft = half ? ext : v[0];     // col 255 | clamp col -1 -> 0
    if (lane == 63) vn0 = half ? v[3] : ext;      // clamp col 512 -> 511 | col 256
    cm[0] = fminf(vleft, v[0]);
    cm[1] = fminf(v[0], v[1]);
    cm[2] = fminf(v[1], v[2]);
    cm[3] = fminf(v[2], v[3]);
    cm[4] = fminf(v[3], vn0);
  };

  // --- prologue: row rs-1 (clamped at image top) ---
  loadrow(strip ? -1 : 0);
#pragma unroll
  for (int k = 0; k < 5; ++k) pcm[k] = cm[k];

  // --- row rs: erosion + its dilation row-max -> dmp ---
  loadrow(0);
  {
    float er[5];
#pragma unroll
    for (int k = 0; k < 5; ++k) er[k] = fminf(pcm[k], cm[k]);
#pragma unroll
    for (int k = 0; k < 4; ++k) dmp[k] = fmaxf(er[k], er[k + 1]);
#pragma unroll
    for (int k = 0; k < 4; ++k) xp[k] = v[k];
#pragma unroll
    for (int k = 0; k < 5; ++k) pcm[k] = cm[k];
  }

  // finish row i using row i+1
  auto advance = [&](int drow_next) {
    loadrow(drow_next);
    float er[5], dm[4];
#pragma unroll
    for (int k = 0; k < 5; ++k) er[k] = fminf(pcm[k], cm[k]);
#pragma unroll
    for (int k = 0; k < 4; ++k) dm[k] = fmaxf(er[k], er[k + 1]);
#pragma unroll
    for (int k = 0; k < 4; ++k) {
      const float d = xp[k] - fmaxf(dmp[k], dm[k]);
      acc = fmaf(d, d, acc);
      xp[k] = v[k]; dmp[k] = dm[k];
    }
#pragma unroll
    for (int k = 0; k < 5; ++k) pcm[k] = cm[k];
  };

  // rows rs .. rs+14: next row always in-bounds
#pragma unroll
  for (int r = 1; r < RPW; ++r) advance(r);

  // row rs+15: next row in-bounds except for the last strip
  if (strip != STRIPS - 1) {
    advance(RPW);
  } else {  // row 511: dilation row 512 clamps to 511 -> di = dmp
#pragma unroll
    for (int k = 0; k < 4; ++k) {
      const float d = xp[k] - dmp[k];
      acc = fmaf(d, d, acc);
    }
  }

  // wave reduce (64 lanes) -> block reduce -> one atomic per block
#pragma unroll
  for (int off = 32; off > 0; off >>= 1) acc += __shfl_down(acc, off);
  __shared__ float sh[4];
  const int wid = threadIdx.x >> 6;
  if (lane == 0) sh[wid] = acc;
  __syncthreads();
  if (threadIdx.x == 0) {
    atomicAdd(out, (sh[0] + sh[1] + sh[2] + sh[3]) * invN);
  }
}

extern "C" void kernel_launch(void* const* d_in, const int* in_sizes, int n_in,
                              void* d_out, int out_size, void* d_ws, size_t ws_size,
                              hipStream_t stream) {
  const float* x = (const float*)d_in[0];
  float* out = (float*)d_out;

  const long long n = in_sizes[0];                 // 16*8*512*512 = 2^25
  const int nImg = (int)(n / ((long long)H * W));  // 128
  const int nWaves = nImg * STRIPS * 2;            // 8192
  const int nBlocks = nWaves / 4;                  // 2048 blocks x 256 thr

  const float invN = 1.0f / (float)n;              // 2^-25, exact

  hipMemsetAsync(out, 0, sizeof(float), stream);   // d_out is poisoned 0xAA
  open_loss<<<nBlocks, 256, 0, stream>>>(x, out, invN);
}